// Round 11
// baseline (198.908 us; speedup 1.0000x reference)
//
#include <hip/hip_runtime.h>
#include <hip/hip_bf16.h>

// GAT layer, N=8192, F_IN=256, F_OUT=64.
// ROUND 11 = DECOMPOSITION PROBE: kernels byte-identical to round 10; k2b and
// k3 are each launched TWICE (idempotent: pure functions of ws buffers that
// are L2/L3-warm in both runs). dur_us delta vs round 10 = dur(k2b)+dur(k3),
// which finally splits the 139 us budget between kA and k2b/k3.
//
//  kA : fused mask-builder + k1, role by wave id.
//  k2b: U = adj@Wh from bitmask via MFMA; dual row-set; Gmax; Upack + A/C.
//  k3 : fused softmax + attention@U + ELU, dual row-set, factorized weights.
//
// Fragment convention (proven rounds 1/3/4/5):
//  element e of lane l <-> k = kblock*32 + (l>>4)*8 + e; A row / B col = l&15;
//  C/D: col = l&15, row = (l>>4)*4 + reg.
//  Bpack/Upack: frag[(kb*4+b)*64 + lane][e]  (s16x8 per lane)
// Mask bit for (row i, col j): word ML[i*128 + (j>>8)*4 + (j&3)], bit (j>>2)&63.

#define N 8192

typedef float f32x4 __attribute__((ext_vector_type(4)));
typedef short s16x8 __attribute__((ext_vector_type(8)));
typedef unsigned long long u64;
typedef u64 u64x2 __attribute__((ext_vector_type(2)));

__device__ __forceinline__ unsigned short f2bf(float x) {
  unsigned u = __float_as_uint(x);
  u += 0x7FFFu + ((u >> 16) & 1u);   // RNE
  return (unsigned short)(u >> 16);
}
__device__ __forceinline__ unsigned pack2(unsigned short lo, unsigned short hi) {
  return (unsigned)lo | ((unsigned)hi << 16);
}

#define MFMA __builtin_amdgcn_mfma_f32_16x16x32_bf16

// ---------------- kA: wave-interleaved mask-builder + k1 ----------------
__global__ __launch_bounds__(256) void kA(const float* __restrict__ adj,
                                          const float* __restrict__ h,
                                          const float* __restrict__ W,
                                          const float* __restrict__ a,
                                          u64* __restrict__ ML,
                                          unsigned short* __restrict__ Bpack,
                                          float* __restrict__ f,
                                          float* __restrict__ g,
                                          float* __restrict__ expg,
                                          float* __restrict__ expg2) {
  const int l = threadIdx.x & 63;
  const int w = threadIdx.x >> 6;
  const int i = (blockIdx.x << 1) + (w & 1);   // row for this wave
  if (w < 2) {
    const float* ap = adj + (size_t)i * N + (l << 2);
    u64* mp = ML + (size_t)i * 128;
    f32x4 v0 = *(const f32x4*)(ap);
    f32x4 v1 = *(const f32x4*)(ap + 256);
    f32x4 v2 = *(const f32x4*)(ap + 512);
    f32x4 v3 = *(const f32x4*)(ap + 768);
    for (int cc = 0; cc < 32; cc += 4) {
      const int cn = (cc < 28) ? (cc + 4) : cc;   // last iter: L1-hot reload
      f32x4 n0 = *(const f32x4*)(ap + ((cn + 0) << 8));
      f32x4 n1 = *(const f32x4*)(ap + ((cn + 1) << 8));
      f32x4 n2 = *(const f32x4*)(ap + ((cn + 2) << 8));
      f32x4 n3 = *(const f32x4*)(ap + ((cn + 3) << 8));
      u64 b0  = __ballot(v0.x > 0.f), b1  = __ballot(v0.y > 0.f);
      u64 b2  = __ballot(v0.z > 0.f), b3  = __ballot(v0.w > 0.f);
      u64 b4  = __ballot(v1.x > 0.f), b5  = __ballot(v1.y > 0.f);
      u64 b6  = __ballot(v1.z > 0.f), b7  = __ballot(v1.w > 0.f);
      u64 b8  = __ballot(v2.x > 0.f), b9  = __ballot(v2.y > 0.f);
      u64 b10 = __ballot(v2.z > 0.f), b11 = __ballot(v2.w > 0.f);
      u64 b12 = __ballot(v3.x > 0.f), b13 = __ballot(v3.y > 0.f);
      u64 b14 = __ballot(v3.z > 0.f), b15 = __ballot(v3.w > 0.f);
      if (l == 0) {
        u64x2* q = (u64x2*)(mp + (cc << 2));
        u64x2 t0; t0.x = b0;  t0.y = b1;  q[0] = t0;
        u64x2 t1; t1.x = b2;  t1.y = b3;  q[1] = t1;
        u64x2 t2; t2.x = b4;  t2.y = b5;  q[2] = t2;
        u64x2 t3; t3.x = b6;  t3.y = b7;  q[3] = t3;
        u64x2 t4; t4.x = b8;  t4.y = b9;  q[4] = t4;
        u64x2 t5; t5.x = b10; t5.y = b11; q[5] = t5;
        u64x2 t6; t6.x = b12; t6.y = b13; q[6] = t6;
        u64x2 t7; t7.x = b14; t7.y = b15; q[7] = t7;
      }
      v0 = n0; v1 = n1; v2 = n2; v3 = n3;
    }
  } else {
    const float* hrow = h + (size_t)i * 256;
    float acc = 0.f;
#pragma unroll 4
    for (int kb = 0; kb < 64; ++kb) {
      f32x4 hv = *(const f32x4*)(hrow + (kb << 2));
      acc += hv.x * W[((kb << 2) + 0) * 64 + l];
      acc += hv.y * W[((kb << 2) + 1) * 64 + l];
      acc += hv.z * W[((kb << 2) + 2) * 64 + l];
      acc += hv.w * W[((kb << 2) + 3) * 64 + l];
    }
    float s1 = acc * a[l];
    float s2 = acc * a[64 + l];
#pragma unroll
    for (int d = 32; d > 0; d >>= 1) {
      s1 += __shfl_xor(s1, d);
      s2 += __shfl_xor(s2, d);
    }
    if (l == 0) {
      f[i] = s1; g[i] = s2;
      expg[i] = __expf(s2);
      expg2[i] = __expf(0.2f * s2);
    }
    const int kb = i >> 5;
    const int b = l >> 4;
    const int lp = (l & 15) | (((i >> 3) & 3) << 4);
    const int e = i & 7;
    Bpack[(((size_t)(kb * 4 + b)) * 64 + lp) * 8 + e] = f2bf(acc);
  }
}

// ---------------- k2b: U from mask via MFMA, dual row-set; A/C factors ----------------
__global__ __launch_bounds__(512) void k2b(const u64* __restrict__ ML,
                                           const unsigned short* __restrict__ Bpack,
                                           const float* __restrict__ g,
                                           const float* __restrict__ f,
                                           unsigned short* __restrict__ Upack,
                                           float* __restrict__ Av,
                                           float* __restrict__ Cv) {
  __shared__ float red[2][8][64][16];   // 64 KB
  __shared__ float gred[2][8][16];
  const int l = threadIdx.x & 63;
  const int w = threadIdx.x >> 6;
  const int i0 = blockIdx.x << 5;          // 32 rows/block
  const int r = l & 15, kg = l >> 4;
  const s16x8* Bv = (const s16x8*)Bpack;
  const u64x2* mrow0 = (const u64x2*)(ML + (size_t)(i0 + r) * 128);
  const u64x2* mrow1 = (const u64x2*)(ML + (size_t)(i0 + 16 + r) * 128);
  const int sh0 = kg << 1;
  f32x4 x0 = {0.f,0.f,0.f,0.f}, x1 = x0, x2 = x0, x3 = x0;   // set0 accs
  f32x4 y0 = x0, y1 = x0, y2 = x0, y3 = x0;                  // set1 accs
  float gmx0 = -INFINITY, gmx1 = -INFINITY;
  for (int cc = 0; cc < 4; ++cc) {
    const int c = (w << 2) + cc;           // chunk of 256 cols
    u64x2 ma = mrow0[(c << 1)], mb = mrow0[(c << 1) + 1];
    const u64 xa0 = ma.x >> sh0, xa1 = ma.y >> sh0,
              xa2 = mb.x >> sh0, xa3 = mb.y >> sh0;
    u64x2 mc = mrow1[(c << 1)], md = mrow1[(c << 1) + 1];
    const u64 ya0 = mc.x >> sh0, ya1 = mc.y >> sh0,
              ya2 = md.x >> sh0, ya3 = md.y >> sh0;
#pragma unroll
    for (int j7 = 0; j7 < 8; ++j7) {
      const int jb = (c << 3) + j7;
      f32x4 g0 = *(const f32x4*)(g + (jb << 5) + (kg << 3));
      f32x4 g1 = *(const f32x4*)(g + (jb << 5) + (kg << 3) + 4);
      const unsigned p0 = (unsigned)(xa0 >> (j7 << 3)) & 1u;
      const unsigned p1 = (unsigned)(xa1 >> (j7 << 3)) & 1u;
      const unsigned p2 = (unsigned)(xa2 >> (j7 << 3)) & 1u;
      const unsigned p3 = (unsigned)(xa3 >> (j7 << 3)) & 1u;
      const unsigned p4 = (unsigned)(xa0 >> ((j7 << 3) + 1)) & 1u;
      const unsigned p5 = (unsigned)(xa1 >> ((j7 << 3) + 1)) & 1u;
      const unsigned p6 = (unsigned)(xa2 >> ((j7 << 3) + 1)) & 1u;
      const unsigned p7 = (unsigned)(xa3 >> ((j7 << 3) + 1)) & 1u;
      const unsigned q0 = (unsigned)(ya0 >> (j7 << 3)) & 1u;
      const unsigned q1 = (unsigned)(ya1 >> (j7 << 3)) & 1u;
      const unsigned q2 = (unsigned)(ya2 >> (j7 << 3)) & 1u;
      const unsigned q3 = (unsigned)(ya3 >> (j7 << 3)) & 1u;
      const unsigned q4 = (unsigned)(ya0 >> ((j7 << 3) + 1)) & 1u;
      const unsigned q5 = (unsigned)(ya1 >> ((j7 << 3) + 1)) & 1u;
      const unsigned q6 = (unsigned)(ya2 >> ((j7 << 3) + 1)) & 1u;
      const unsigned q7 = (unsigned)(ya3 >> ((j7 << 3) + 1)) & 1u;
      s16x8 af0, af1;
      af0[0] = p0 ? (short)0x3F80 : (short)0;
      af0[1] = p1 ? (short)0x3F80 : (short)0;
      af0[2] = p2 ? (short)0x3F80 : (short)0;
      af0[3] = p3 ? (short)0x3F80 : (short)0;
      af0[4] = p4 ? (short)0x3F80 : (short)0;
      af0[5] = p5 ? (short)0x3F80 : (short)0;
      af0[6] = p6 ? (short)0x3F80 : (short)0;
      af0[7] = p7 ? (short)0x3F80 : (short)0;
      af1[0] = q0 ? (short)0x3F80 : (short)0;
      af1[1] = q1 ? (short)0x3F80 : (short)0;
      af1[2] = q2 ? (short)0x3F80 : (short)0;
      af1[3] = q3 ? (short)0x3F80 : (short)0;
      af1[4] = q4 ? (short)0x3F80 : (short)0;
      af1[5] = q5 ? (short)0x3F80 : (short)0;
      af1[6] = q6 ? (short)0x3F80 : (short)0;
      af1[7] = q7 ? (short)0x3F80 : (short)0;
      if (p0) gmx0 = fmaxf(gmx0, g0.x);
      if (p1) gmx0 = fmaxf(gmx0, g0.y);
      if (p2) gmx0 = fmaxf(gmx0, g0.z);
      if (p3) gmx0 = fmaxf(gmx0, g0.w);
      if (p4) gmx0 = fmaxf(gmx0, g1.x);
      if (p5) gmx0 = fmaxf(gmx0, g1.y);
      if (p6) gmx0 = fmaxf(gmx0, g1.z);
      if (p7) gmx0 = fmaxf(gmx0, g1.w);
      if (q0) gmx1 = fmaxf(gmx1, g0.x);
      if (q1) gmx1 = fmaxf(gmx1, g0.y);
      if (q2) gmx1 = fmaxf(gmx1, g0.z);
      if (q3) gmx1 = fmaxf(gmx1, g0.w);
      if (q4) gmx1 = fmaxf(gmx1, g1.x);
      if (q5) gmx1 = fmaxf(gmx1, g1.y);
      if (q6) gmx1 = fmaxf(gmx1, g1.z);
      if (q7) gmx1 = fmaxf(gmx1, g1.w);
      const size_t bi = ((size_t)jb << 8) + l;
      s16x8 f0 = Bv[bi], f1 = Bv[bi + 64], f2 = Bv[bi + 128], f3 = Bv[bi + 192];
      x0 = MFMA(af0, f0, x0, 0, 0, 0);
      x1 = MFMA(af0, f1, x1, 0, 0, 0);
      x2 = MFMA(af0, f2, x2, 0, 0, 0);
      x3 = MFMA(af0, f3, x3, 0, 0, 0);
      y0 = MFMA(af1, f0, y0, 0, 0, 0);
      y1 = MFMA(af1, f1, y1, 0, 0, 0);
      y2 = MFMA(af1, f2, y2, 0, 0, 0);
      y3 = MFMA(af1, f3, y3, 0, 0, 0);
    }
  }
  gmx0 = fmaxf(gmx0, __shfl_xor(gmx0, 16));
  gmx0 = fmaxf(gmx0, __shfl_xor(gmx0, 32));
  gmx1 = fmaxf(gmx1, __shfl_xor(gmx1, 16));
  gmx1 = fmaxf(gmx1, __shfl_xor(gmx1, 32));
  if (l < 16) { gred[0][w][l] = gmx0; gred[1][w][l] = gmx1; }
#pragma unroll
  for (int q = 0; q < 4; ++q) {
    red[0][w][l][q] = x0[q]; red[0][w][l][4 + q] = x1[q];
    red[0][w][l][8 + q] = x2[q]; red[0][w][l][12 + q] = x3[q];
    red[1][w][l][q] = y0[q]; red[1][w][l][4 + q] = y1[q];
    red[1][w][l][8 + q] = y2[q]; red[1][w][l][12 + q] = y3[q];
  }
  __syncthreads();
  const int tl = threadIdx.x & 63;
  const int b = (threadIdx.x >> 6) & 3;
  const int sE = threadIdx.x >> 8;
  const int reg0 = sE << 1;
#pragma unroll
  for (int s = 0; s < 2; ++s) {
    float u0 = 0.f, u1 = 0.f;
#pragma unroll
    for (int w8 = 0; w8 < 8; ++w8) {
      u0 += red[s][w8][tl][(b << 2) + reg0];
      u1 += red[s][w8][tl][(b << 2) + reg0 + 1];
    }
    const int k0 = i0 + (s << 4) + ((tl >> 4) << 2) + reg0;
    const unsigned pkv = pack2(f2bf(u0), f2bf(u1));
    const int kbD = k0 >> 5, lgrp = (k0 >> 3) & 3, e0 = k0 & 7;
    *(unsigned*)((char*)Upack +
        ((size_t)((kbD << 2) + b) * 64 + ((tl & 15) | (lgrp << 4))) * 16 + (e0 << 1)) = pkv;
  }
  if (threadIdx.x < 32) {
    const int s2 = threadIdx.x >> 4, rr = threadIdx.x & 15;
    float gm = gred[s2][0][rr];
#pragma unroll
    for (int w8 = 1; w8 < 8; ++w8) gm = fmaxf(gm, gred[s2][w8][rr]);
    const int i = i0 + (s2 << 4) + rr;
    const float fv = f[i];
    float mm = fv + gm;
    mm = fmaxf(mm, 0.2f * mm);             // m_i = leaky(f_i + Gmax_i)
    Av[i] = __expf(fv - mm);
    Cv[i] = __expf(0.2f * fv - mm);
  }
}

// ---------------- k3: fused softmax + attention@U + ELU, dual row-set ----------------
__global__ __launch_bounds__(512) void k3(const u64* __restrict__ ML,
                                          const unsigned short* __restrict__ Upack,
                                          const float* __restrict__ f,
                                          const float* __restrict__ expg,
                                          const float* __restrict__ expg2,
                                          const float* __restrict__ Av,
                                          const float* __restrict__ Cv,
                                          float* __restrict__ out) {
  __shared__ float red[2][8][64][16];   // 64 KB
  __shared__ float wred[2][8][16];
  const int l = threadIdx.x & 63;
  const int w = threadIdx.x >> 6;
  const int i0 = blockIdx.x << 5;
  const int r = l & 15, kg = l >> 4;
  const float enf0 = __expf(-f[i0 + r]);
  const float enf1 = __expf(-f[i0 + 16 + r]);
  const float Ar0 = Av[i0 + r],      Cr0 = Cv[i0 + r];
  const float Ar1 = Av[i0 + 16 + r], Cr1 = Cv[i0 + 16 + r];
  const s16x8* Uv = (const s16x8*)Upack;
  const u64x2* mrow0 = (const u64x2*)(ML + (size_t)(i0 + r) * 128);
  const u64x2* mrow1 = (const u64x2*)(ML + (size_t)(i0 + 16 + r) * 128);
  const int sh0 = kg << 1;
  f32x4 x0 = {0.f,0.f,0.f,0.f}, x1 = x0, x2 = x0, x3 = x0;
  f32x4 y0 = x0, y1 = x0, y2 = x0, y3 = x0;
  float ws0 = 0.f, ws1 = 0.f;
  for (int cc = 0; cc < 4; ++cc) {
    const int c = (w << 2) + cc;
    u64x2 ma = mrow0[(c << 1)], mb = mrow0[(c << 1) + 1];
    const u64 xa0 = ma.x >> sh0, xa1 = ma.y >> sh0,
              xa2 = mb.x >> sh0, xa3 = mb.y >> sh0;
    u64x2 mc = mrow1[(c << 1)], md = mrow1[(c << 1) + 1];
    const u64 ya0 = mc.x >> sh0, ya1 = mc.y >> sh0,
              ya2 = md.x >> sh0, ya3 = md.y >> sh0;
#pragma unroll
    for (int j7 = 0; j7 < 8; ++j7) {
      const int jb = (c << 3) + j7;
      f32x4 eg0 = *(const f32x4*)(expg + (jb << 5) + (kg << 3));
      f32x4 eg1 = *(const f32x4*)(expg + (jb << 5) + (kg << 3) + 4);
      f32x4 eh0 = *(const f32x4*)(expg2 + (jb << 5) + (kg << 3));
      f32x4 eh1 = *(const f32x4*)(expg2 + (jb << 5) + (kg << 3) + 4);
      s16x8 pf0, pf1;
#define K3W(pf, idx, wq, sh, egv, ehv, enf, Ar, Cr, wsv) {   \
      const unsigned bit_ = (unsigned)((wq) >> (sh)) & 1u;   \
      const bool sg_ = (egv) > (enf);                        \
      float t_ = sg_ ? (Ar) : (Cr);                          \
      float u_ = sg_ ? (egv) : (ehv);                        \
      float wt_ = t_ * u_;                                   \
      wt_ = bit_ ? wt_ : 0.f;                                \
      wsv += wt_; pf[idx] = (short)f2bf(wt_); }
      K3W(pf0, 0, xa0, (j7 << 3),     eg0.x, eh0.x, enf0, Ar0, Cr0, ws0)
      K3W(pf0, 1, xa1, (j7 << 3),     eg0.y, eh0.y, enf0, Ar0, Cr0, ws0)
      K3W(pf0, 2, xa2, (j7 << 3),     eg0.z, eh0.z, enf0, Ar0, Cr0, ws0)
      K3W(pf0, 3, xa3, (j7 << 3),     eg0.w, eh0.w, enf0, Ar0, Cr0, ws0)
      K3W(pf0, 4, xa0, (j7 << 3) + 1, eg1.x, eh1.x, enf0, Ar0, Cr0, ws0)
      K3W(pf0, 5, xa1, (j7 << 3) + 1, eg1.y, eh1.y, enf0, Ar0, Cr0, ws0)
      K3W(pf0, 6, xa2, (j7 << 3) + 1, eg1.z, eh1.z, enf0, Ar0, Cr0, ws0)
      K3W(pf0, 7, xa3, (j7 << 3) + 1, eg1.w, eh1.w, enf0, Ar0, Cr0, ws0)
      K3W(pf1, 0, ya0, (j7 << 3),     eg0.x, eh0.x, enf1, Ar1, Cr1, ws1)
      K3W(pf1, 1, ya1, (j7 << 3),     eg0.y, eh0.y, enf1, Ar1, Cr1, ws1)
      K3W(pf1, 2, ya2, (j7 << 3),     eg0.z, eh0.z, enf1, Ar1, Cr1, ws1)
      K3W(pf1, 3, ya3, (j7 << 3),     eg0.w, eh0.w, enf1, Ar1, Cr1, ws1)
      K3W(pf1, 4, ya0, (j7 << 3) + 1, eg1.x, eh1.x, enf1, Ar1, Cr1, ws1)
      K3W(pf1, 5, ya1, (j7 << 3) + 1, eg1.y, eh1.y, enf1, Ar1, Cr1, ws1)
      K3W(pf1, 6, ya2, (j7 << 3) + 1, eg1.z, eh1.z, enf1, Ar1, Cr1, ws1)
      K3W(pf1, 7, ya3, (j7 << 3) + 1, eg1.w, eh1.w, enf1, Ar1, Cr1, ws1)
#undef K3W
      const size_t bi = ((size_t)jb << 8) + l;
      s16x8 f0 = Uv[bi], f1 = Uv[bi + 64], f2 = Uv[bi + 128], f3 = Uv[bi + 192];
      x0 = MFMA(pf0, f0, x0, 0, 0, 0);
      x1 = MFMA(pf0, f1, x1, 0, 0, 0);
      x2 = MFMA(pf0, f2, x2, 0, 0, 0);
      x3 = MFMA(pf0, f3, x3, 0, 0, 0);
      y0 = MFMA(pf1, f0, y0, 0, 0, 0);
      y1 = MFMA(pf1, f1, y1, 0, 0, 0);
      y2 = MFMA(pf1, f2, y2, 0, 0, 0);
      y3 = MFMA(pf1, f3, y3, 0, 0, 0);
    }
  }
  ws0 += __shfl_xor(ws0, 16);
  ws0 += __shfl_xor(ws0, 32);
  ws1 += __shfl_xor(ws1, 16);
  ws1 += __shfl_xor(ws1, 32);
  if (l < 16) { wred[0][w][l] = ws0; wred[1][w][l] = ws1; }
#pragma unroll
  for (int q = 0; q < 4; ++q) {
    red[0][w][l][q] = x0[q]; red[0][w][l][4 + q] = x1[q];
    red[0][w][l][8 + q] = x2[q]; red[0][w][l][12 + q] = x3[q];
    red[1][w][l][q] = y0[q]; red[1][w][l][4 + q] = y1[q];
    red[1][w][l][8 + q] = y2[q]; red[1][w][l][12 + q] = y3[q];
  }
  __syncthreads();
  const int tl = threadIdx.x & 63;
  const int b = (threadIdx.x >> 6) & 3;
  const int sE = threadIdx.x >> 8;
#pragma unroll
  for (int s = 0; s < 2; ++s) {
#pragma unroll
    for (int q = 0; q < 2; ++q) {
      const int reg = (sE << 1) + q;
      const int idx = (b << 2) + reg;
      const int row = ((tl >> 4) << 2) + reg;
      float sv = 0.f, dv = 0.f;
#pragma unroll
      for (int w8 = 0; w8 < 8; ++w8) {
        sv += red[s][w8][tl][idx];
        dv += wred[s][w8][row];
      }
      dv = (dv > 0.f) ? dv : 1.f;            // defensive: avoid 0/0
      float v = sv / dv;
      v = (v > 0.f) ? v : (__expf(v) - 1.f); // ELU
      out[(size_t)(i0 + (s << 4) + row) * 64 + (b << 4) + (tl & 15)] = v;
    }
  }
}

extern "C" void kernel_launch(void* const* d_in, const int* in_sizes, int n_in,
                              void* d_out, int out_size, void* d_ws, size_t ws_size,
                              hipStream_t stream) {
  const float* h   = (const float*)d_in[0];
  const float* adj = (const float*)d_in[1];
  const float* W   = (const float*)d_in[2];
  const float* a   = (const float*)d_in[3];
  float* out = (float*)d_out;
  char* ws = (char*)d_ws;
  unsigned short* Bpack = (unsigned short*)(ws);                   // 1 MB
  unsigned short* Upack = (unsigned short*)(ws + (1u << 20));      // 1 MB
  float* f     = (float*)(ws + (2u << 20));                        // 32 KB
  float* g     = (float*)(ws + (2u << 20) + 1u * 32768u);          // 32 KB
  float* expg  = (float*)(ws + (2u << 20) + 2u * 32768u);          // 32 KB
  float* expg2 = (float*)(ws + (2u << 20) + 3u * 32768u);          // 32 KB
  float* Av    = (float*)(ws + (2u << 20) + 4u * 32768u);          // 32 KB
  float* Cv    = (float*)(ws + (2u << 20) + 5u * 32768u);          // 32 KB
  u64* ML = (u64*)(ws + (3u << 20));                               // 8 MB

  hipLaunchKernelGGL(kA,  dim3(4096), dim3(256), 0, stream,
                     adj, h, W, a, ML, Bpack, f, g, expg, expg2);
  hipLaunchKernelGGL(k2b, dim3(256), dim3(512), 0, stream,
                     ML, Bpack, g, f, Upack, Av, Cv);
  hipLaunchKernelGGL(k3,  dim3(256), dim3(512), 0, stream,
                     ML, Upack, f, expg, expg2, Av, Cv, out);
  // --- decomposition probe: idempotent re-runs (inputs L2/L3-warm) ---
  hipLaunchKernelGGL(k2b, dim3(256), dim3(512), 0, stream,
                     ML, Bpack, g, f, Upack, Av, Cv);
  hipLaunchKernelGGL(k3,  dim3(256), dim3(512), 0, stream,
                     ML, Upack, f, expg, expg2, Av, Cv, out);
}

// Round 12
// 150.856 us; speedup vs baseline: 1.3185x; 1.3185x over previous
//
#include <hip/hip_runtime.h>
#include <hip/hip_bf16.h>

// GAT layer, N=8192, F_IN=256, F_OUT=64.
//  kA : bid<1024  -> adj stream role: fill-like GLOBAL SWEEP over 1KB chunks
//        (grid-stride, consecutive waves = consecutive addresses, nontemporal,
//        8KB in flight/wave). ML[i][c][q] bit l = adj[i][c*256 + l*4 + q] > 0.
//       bid>=1024 -> k1 role: scalar Wh = h@W; per-row factors expg=exp(g),
//        expg2=exp(.2g), Af=exp(f), Cf=exp(.2f), Enf=exp(-f); Bpack (bf16
//        B-frags of Wh). NO max-subtraction anywhere: |e|<=~2.6 so exp is safe
//        and softmax is scale-invariant.
//  k2b: U = adj@Wh from bitmask via MFMA; dual row-set; lean loop (no gmx/g).
//  k3 : fused softmax + attention@U + ELU, dual row-set; weights
//       w_ij = (eg_j > Enf_i) ? Af_i*eg_j : Cf_i*eg2_j, masked; denominator via
//       MFMA with an all-ones B fragment (P@1 = rowsum); cheap rn-bf16 pack.
//
// Fragment convention (proven rounds 1/3/4/5):
//  element e of lane l <-> k = kblock*32 + (l>>4)*8 + e; A row / B col = l&15;
//  C/D: col = l&15, row = (l>>4)*4 + reg.
//  Bpack/Upack: frag[(kb*4+b)*64 + lane][e]  (s16x8 per lane)
// Mask bit for (row i, col j): word ML[i*128 + (j>>8)*4 + (j&3)], bit (j>>2)&63.
//  For fragment element (r, jb, kg, e): word (jb>>3)*4 + (e&3),
//  shift = (jb&7)*8 + kg*2 + (e>>2). Pre-shift by sh0=kg*2 per chunk.

#define N 8192

typedef float f32x4 __attribute__((ext_vector_type(4)));
typedef short s16x8 __attribute__((ext_vector_type(8)));
typedef unsigned long long u64;
typedef u64 u64x2 __attribute__((ext_vector_type(2)));

union PF { s16x8 v; unsigned u[4]; };

__device__ __forceinline__ unsigned short f2bf(float x) {
  unsigned u = __float_as_uint(x);
  u += 0x7FFFu + ((u >> 16) & 1u);   // RNE
  return (unsigned short)(u >> 16);
}
__device__ __forceinline__ unsigned pack2(unsigned short lo, unsigned short hi) {
  return (unsigned)lo | ((unsigned)hi << 16);
}
// round-half-up bf16 pair pack (2 ops/elem; wt is small positive => safe)
__device__ __forceinline__ unsigned packrn(float lo, float hi) {
  return ((__float_as_uint(lo) + 0x8000u) >> 16) |
         ((__float_as_uint(hi) + 0x8000u) & 0xFFFF0000u);
}

#define MFMA __builtin_amdgcn_mfma_f32_16x16x32_bf16

// ---------------- kA: sweep-order mask builder (bid<1024) + k1 (bid>=1024) ----------------
__global__ __launch_bounds__(256) void kA(const float* __restrict__ adj,
                                          const float* __restrict__ h,
                                          const float* __restrict__ W,
                                          const float* __restrict__ a,
                                          u64* __restrict__ ML,
                                          unsigned short* __restrict__ Bpack,
                                          float* __restrict__ expg,
                                          float* __restrict__ expg2,
                                          float* __restrict__ Af,
                                          float* __restrict__ Cf,
                                          float* __restrict__ Enf) {
  const int l = threadIdx.x & 63;
  const int w = threadIdx.x >> 6;
  const int bid = blockIdx.x;
  if (bid < 1024) {
    // ----- stream role: global sweep, 8 chunks (8KB) per iteration -----
    const int wid = (bid << 2) + w;            // 0..4095
    for (int it = 0; it < 8; ++it) {
      const int ch0 = wid + it * 32768;        // + k*4096, k = 0..7
      f32x4 v0 = __builtin_nontemporal_load((const f32x4*)(adj + (((size_t)(ch0          )) << 8) + (l << 2)));
      f32x4 v1 = __builtin_nontemporal_load((const f32x4*)(adj + (((size_t)(ch0 +  4096)) << 8) + (l << 2)));
      f32x4 v2 = __builtin_nontemporal_load((const f32x4*)(adj + (((size_t)(ch0 +  8192)) << 8) + (l << 2)));
      f32x4 v3 = __builtin_nontemporal_load((const f32x4*)(adj + (((size_t)(ch0 + 12288)) << 8) + (l << 2)));
      f32x4 v4 = __builtin_nontemporal_load((const f32x4*)(adj + (((size_t)(ch0 + 16384)) << 8) + (l << 2)));
      f32x4 v5 = __builtin_nontemporal_load((const f32x4*)(adj + (((size_t)(ch0 + 20480)) << 8) + (l << 2)));
      f32x4 v6 = __builtin_nontemporal_load((const f32x4*)(adj + (((size_t)(ch0 + 24576)) << 8) + (l << 2)));
      f32x4 v7 = __builtin_nontemporal_load((const f32x4*)(adj + (((size_t)(ch0 + 28672)) << 8) + (l << 2)));
#define KCHUNK(vk, koff) {                                                    \
      const int ch = ch0 + (koff);                                            \
      u64 b0 = __ballot(vk.x > 0.f);                                          \
      u64 b1 = __ballot(vk.y > 0.f);                                          \
      u64 b2 = __ballot(vk.z > 0.f);                                          \
      u64 b3 = __ballot(vk.w > 0.f);                                          \
      if (l == 0) {                                                           \
        u64x2* q = (u64x2*)(ML + (((size_t)(ch >> 5)) << 7) + ((ch & 31) << 2)); \
        u64x2 t0; t0.x = b0; t0.y = b1;                                       \
        u64x2 t1; t1.x = b2; t1.y = b3;                                       \
        q[0] = t0; q[1] = t1;                                                 \
      } }
      KCHUNK(v0, 0)     KCHUNK(v1, 4096)  KCHUNK(v2, 8192)  KCHUNK(v3, 12288)
      KCHUNK(v4, 16384) KCHUNK(v5, 20480) KCHUNK(v6, 24576) KCHUNK(v7, 28672)
#undef KCHUNK
    }
  } else {
    // ----- k1 role: one row per wave (round-5-proven body + factor stores) -----
    const int i = ((bid - 1024) << 2) + w;
    const float* hrow = h + (size_t)i * 256;
    float acc = 0.f;
#pragma unroll 4
    for (int kb = 0; kb < 64; ++kb) {
      f32x4 hv = *(const f32x4*)(hrow + (kb << 2));
      acc += hv.x * W[((kb << 2) + 0) * 64 + l];
      acc += hv.y * W[((kb << 2) + 1) * 64 + l];
      acc += hv.z * W[((kb << 2) + 2) * 64 + l];
      acc += hv.w * W[((kb << 2) + 3) * 64 + l];
    }
    float s1 = acc * a[l];
    float s2 = acc * a[64 + l];
#pragma unroll
    for (int d = 32; d > 0; d >>= 1) {
      s1 += __shfl_xor(s1, d);
      s2 += __shfl_xor(s2, d);
    }
    if (l == 0) {
      expg[i]  = __expf(s2);
      expg2[i] = __expf(0.2f * s2);
      Af[i]    = __expf(s1);
      Cf[i]    = __expf(0.2f * s1);
      Enf[i]   = __expf(-s1);
    }
    const int kb = i >> 5;
    const int b = l >> 4;
    const int lp = (l & 15) | (((i >> 3) & 3) << 4);
    const int e = i & 7;
    Bpack[(((size_t)(kb * 4 + b)) * 64 + lp) * 8 + e] = f2bf(acc);
  }
}

// ---------------- k2b: U from mask via MFMA, dual row-set (lean) ----------------
__global__ __launch_bounds__(512) void k2b(const u64* __restrict__ ML,
                                           const unsigned short* __restrict__ Bpack,
                                           unsigned short* __restrict__ Upack) {
  __shared__ float red[2][8][64][16];   // 64 KB
  const int l = threadIdx.x & 63;
  const int w = threadIdx.x >> 6;
  const int i0 = blockIdx.x << 5;          // 32 rows/block
  const int r = l & 15, kg = l >> 4;
  const s16x8* Bv = (const s16x8*)Bpack;
  const u64x2* mrow0 = (const u64x2*)(ML + (size_t)(i0 + r) * 128);
  const u64x2* mrow1 = (const u64x2*)(ML + (size_t)(i0 + 16 + r) * 128);
  const int sh0 = kg << 1;
  f32x4 x0 = {0.f,0.f,0.f,0.f}, x1 = x0, x2 = x0, x3 = x0;
  f32x4 y0 = x0, y1 = x0, y2 = x0, y3 = x0;
  for (int cc = 0; cc < 4; ++cc) {
    const int c = (w << 2) + cc;           // chunk of 256 cols
    u64x2 ma = mrow0[(c << 1)], mb = mrow0[(c << 1) + 1];
    const u64 xa0 = ma.x >> sh0, xa1 = ma.y >> sh0,
              xa2 = mb.x >> sh0, xa3 = mb.y >> sh0;
    u64x2 mc = mrow1[(c << 1)], md = mrow1[(c << 1) + 1];
    const u64 ya0 = mc.x >> sh0, ya1 = mc.y >> sh0,
              ya2 = md.x >> sh0, ya3 = md.y >> sh0;
#pragma unroll
    for (int j7 = 0; j7 < 8; ++j7) {
      const int jb = (c << 3) + j7;
      const unsigned p0 = (unsigned)(xa0 >> (j7 << 3)) & 1u;
      const unsigned p1 = (unsigned)(xa1 >> (j7 << 3)) & 1u;
      const unsigned p2 = (unsigned)(xa2 >> (j7 << 3)) & 1u;
      const unsigned p3 = (unsigned)(xa3 >> (j7 << 3)) & 1u;
      const unsigned p4 = (unsigned)(xa0 >> ((j7 << 3) + 1)) & 1u;
      const unsigned p5 = (unsigned)(xa1 >> ((j7 << 3) + 1)) & 1u;
      const unsigned p6 = (unsigned)(xa2 >> ((j7 << 3) + 1)) & 1u;
      const unsigned p7 = (unsigned)(xa3 >> ((j7 << 3) + 1)) & 1u;
      const unsigned q0 = (unsigned)(ya0 >> (j7 << 3)) & 1u;
      const unsigned q1 = (unsigned)(ya1 >> (j7 << 3)) & 1u;
      const unsigned q2 = (unsigned)(ya2 >> (j7 << 3)) & 1u;
      const unsigned q3 = (unsigned)(ya3 >> (j7 << 3)) & 1u;
      const unsigned q4 = (unsigned)(ya0 >> ((j7 << 3) + 1)) & 1u;
      const unsigned q5 = (unsigned)(ya1 >> ((j7 << 3) + 1)) & 1u;
      const unsigned q6 = (unsigned)(ya2 >> ((j7 << 3) + 1)) & 1u;
      const unsigned q7 = (unsigned)(ya3 >> ((j7 << 3) + 1)) & 1u;
      s16x8 af0, af1;
      af0[0] = p0 ? (short)0x3F80 : (short)0;
      af0[1] = p1 ? (short)0x3F80 : (short)0;
      af0[2] = p2 ? (short)0x3F80 : (short)0;
      af0[3] = p3 ? (short)0x3F80 : (short)0;
      af0[4] = p4 ? (short)0x3F80 : (short)0;
      af0[5] = p5 ? (short)0x3F80 : (short)0;
      af0[6] = p6 ? (short)0x3F80 : (short)0;
      af0[7] = p7 ? (short)0x3F80 : (short)0;
      af1[0] = q0 ? (short)0x3F80 : (short)0;
      af1[1] = q1 ? (short)0x3F80 : (short)0;
      af1[2] = q2 ? (short)0x3F80 : (short)0;
      af1[3] = q3 ? (short)0x3F80 : (short)0;
      af1[4] = q4 ? (short)0x3F80 : (short)0;
      af1[5] = q5 ? (short)0x3F80 : (short)0;
      af1[6] = q6 ? (short)0x3F80 : (short)0;
      af1[7] = q7 ? (short)0x3F80 : (short)0;
      const size_t bi = ((size_t)jb << 8) + l;
      s16x8 f0 = Bv[bi], f1 = Bv[bi + 64], f2 = Bv[bi + 128], f3 = Bv[bi + 192];
      x0 = MFMA(af0, f0, x0, 0, 0, 0);
      x1 = MFMA(af0, f1, x1, 0, 0, 0);
      x2 = MFMA(af0, f2, x2, 0, 0, 0);
      x3 = MFMA(af0, f3, x3, 0, 0, 0);
      y0 = MFMA(af1, f0, y0, 0, 0, 0);
      y1 = MFMA(af1, f1, y1, 0, 0, 0);
      y2 = MFMA(af1, f2, y2, 0, 0, 0);
      y3 = MFMA(af1, f3, y3, 0, 0, 0);
    }
  }
#pragma unroll
  for (int q = 0; q < 4; ++q) {
    red[0][w][l][q] = x0[q]; red[0][w][l][4 + q] = x1[q];
    red[0][w][l][8 + q] = x2[q]; red[0][w][l][12 + q] = x3[q];
    red[1][w][l][q] = y0[q]; red[1][w][l][4 + q] = y1[q];
    red[1][w][l][8 + q] = y2[q]; red[1][w][l][12 + q] = y3[q];
  }
  __syncthreads();
  const int tl = threadIdx.x & 63;
  const int b = (threadIdx.x >> 6) & 3;
  const int sE = threadIdx.x >> 8;
  const int reg0 = sE << 1;
#pragma unroll
  for (int s = 0; s < 2; ++s) {
    float u0 = 0.f, u1 = 0.f;
#pragma unroll
    for (int w8 = 0; w8 < 8; ++w8) {
      u0 += red[s][w8][tl][(b << 2) + reg0];
      u1 += red[s][w8][tl][(b << 2) + reg0 + 1];
    }
    const int k0 = i0 + (s << 4) + ((tl >> 4) << 2) + reg0;
    const unsigned pkv = pack2(f2bf(u0), f2bf(u1));
    const int kbD = k0 >> 5, lgrp = (k0 >> 3) & 3, e0 = k0 & 7;
    *(unsigned*)((char*)Upack +
        ((size_t)((kbD << 2) + b) * 64 + ((tl & 15) | (lgrp << 4))) * 16 + (e0 << 1)) = pkv;
  }
}

// ---------------- k3: fused softmax + attention@U + ELU, dual row-set ----------------
__global__ __launch_bounds__(512) void k3(const u64* __restrict__ ML,
                                          const unsigned short* __restrict__ Upack,
                                          const float* __restrict__ expg,
                                          const float* __restrict__ expg2,
                                          const float* __restrict__ Af,
                                          const float* __restrict__ Cf,
                                          const float* __restrict__ Enf,
                                          float* __restrict__ out) {
  __shared__ float red[2][8][64][16];   // 64 KB
  __shared__ float wred[2][8][16];
  const int l = threadIdx.x & 63;
  const int w = threadIdx.x >> 6;
  const int i0 = blockIdx.x << 5;
  const int r = l & 15, kg = l >> 4;
  const float enf0 = Enf[i0 + r],      enf1 = Enf[i0 + 16 + r];
  const float Ar0 = Af[i0 + r],        Cr0 = Cf[i0 + r];
  const float Ar1 = Af[i0 + 16 + r],   Cr1 = Cf[i0 + 16 + r];
  const s16x8* Uv = (const s16x8*)Upack;
  const u64x2* mrow0 = (const u64x2*)(ML + (size_t)(i0 + r) * 128);
  const u64x2* mrow1 = (const u64x2*)(ML + (size_t)(i0 + 16 + r) * 128);
  const int sh0 = kg << 1;
  const s16x8 ones = {(short)0x3F80, (short)0x3F80, (short)0x3F80, (short)0x3F80,
                      (short)0x3F80, (short)0x3F80, (short)0x3F80, (short)0x3F80};
  f32x4 x0 = {0.f,0.f,0.f,0.f}, x1 = x0, x2 = x0, x3 = x0, xd = x0;
  f32x4 y0 = x0, y1 = x0, y2 = x0, y3 = x0, yd = x0;
  for (int cc = 0; cc < 4; ++cc) {
    const int c = (w << 2) + cc;
    u64x2 ma = mrow0[(c << 1)], mb = mrow0[(c << 1) + 1];
    const u64 xa0 = ma.x >> sh0, xa1 = ma.y >> sh0,
              xa2 = mb.x >> sh0, xa3 = mb.y >> sh0;
    u64x2 mc = mrow1[(c << 1)], md = mrow1[(c << 1) + 1];
    const u64 ya0 = mc.x >> sh0, ya1 = mc.y >> sh0,
              ya2 = md.x >> sh0, ya3 = md.y >> sh0;
#pragma unroll
    for (int j7 = 0; j7 < 8; ++j7) {
      const int jb = (c << 3) + j7;
      f32x4 eg0 = *(const f32x4*)(expg + (jb << 5) + (kg << 3));
      f32x4 eg1 = *(const f32x4*)(expg + (jb << 5) + (kg << 3) + 4);
      f32x4 eh0 = *(const f32x4*)(expg2 + (jb << 5) + (kg << 3));
      f32x4 eh1 = *(const f32x4*)(expg2 + (jb << 5) + (kg << 3) + 4);
#define WT(wq, sh, egv, ehv, enf, Ar, Cr)                                    \
      ((((wq) >> (sh)) & 1ull) ?                                             \
        (((egv) > (enf)) ? (Ar) * (egv) : (Cr) * (ehv)) : 0.f)
      const float w00 = WT(xa0, (j7 << 3),     eg0.x, eh0.x, enf0, Ar0, Cr0);
      const float w01 = WT(xa1, (j7 << 3),     eg0.y, eh0.y, enf0, Ar0, Cr0);
      const float w02 = WT(xa2, (j7 << 3),     eg0.z, eh0.z, enf0, Ar0, Cr0);
      const float w03 = WT(xa3, (j7 << 3),     eg0.w, eh0.w, enf0, Ar0, Cr0);
      const float w04 = WT(xa0, (j7 << 3) + 1, eg1.x, eh1.x, enf0, Ar0, Cr0);
      const float w05 = WT(xa1, (j7 << 3) + 1, eg1.y, eh1.y, enf0, Ar0, Cr0);
      const float w06 = WT(xa2, (j7 << 3) + 1, eg1.z, eh1.z, enf0, Ar0, Cr0);
      const float w07 = WT(xa3, (j7 << 3) + 1, eg1.w, eh1.w, enf0, Ar0, Cr0);
      const float w10 = WT(ya0, (j7 << 3),     eg0.x, eh0.x, enf1, Ar1, Cr1);
      const float w11 = WT(ya1, (j7 << 3),     eg0.y, eh0.y, enf1, Ar1, Cr1);
      const float w12 = WT(ya2, (j7 << 3),     eg0.z, eh0.z, enf1, Ar1, Cr1);
      const float w13 = WT(ya3, (j7 << 3),     eg0.w, eh0.w, enf1, Ar1, Cr1);
      const float w14 = WT(ya0, (j7 << 3) + 1, eg1.x, eh1.x, enf1, Ar1, Cr1);
      const float w15 = WT(ya1, (j7 << 3) + 1, eg1.y, eh1.y, enf1, Ar1, Cr1);
      const float w16 = WT(ya2, (j7 << 3) + 1, eg1.z, eh1.z, enf1, Ar1, Cr1);
      const float w17 = WT(ya3, (j7 << 3) + 1, eg1.w, eh1.w, enf1, Ar1, Cr1);
#undef WT
      PF pf0, pf1;
      pf0.u[0] = packrn(w00, w01); pf0.u[1] = packrn(w02, w03);
      pf0.u[2] = packrn(w04, w05); pf0.u[3] = packrn(w06, w07);
      pf1.u[0] = packrn(w10, w11); pf1.u[1] = packrn(w12, w13);
      pf1.u[2] = packrn(w14, w15); pf1.u[3] = packrn(w16, w17);
      const size_t bi = ((size_t)jb << 8) + l;
      s16x8 f0 = Uv[bi], f1 = Uv[bi + 64], f2 = Uv[bi + 128], f3 = Uv[bi + 192];
      x0 = MFMA(pf0.v, f0, x0, 0, 0, 0);
      x1 = MFMA(pf0.v, f1, x1, 0, 0, 0);
      x2 = MFMA(pf0.v, f2, x2, 0, 0, 0);
      x3 = MFMA(pf0.v, f3, x3, 0, 0, 0);
      xd = MFMA(pf0.v, ones, xd, 0, 0, 0);
      y0 = MFMA(pf1.v, f0, y0, 0, 0, 0);
      y1 = MFMA(pf1.v, f1, y1, 0, 0, 0);
      y2 = MFMA(pf1.v, f2, y2, 0, 0, 0);
      y3 = MFMA(pf1.v, f3, y3, 0, 0, 0);
      yd = MFMA(pf1.v, ones, yd, 0, 0, 0);
    }
  }
  if (r == 0) {
#pragma unroll
    for (int q = 0; q < 4; ++q) {
      wred[0][w][(kg << 2) + q] = xd[q];   // rowsum: row=(l>>4)*4+q, all cols equal
      wred[1][w][(kg << 2) + q] = yd[q];
    }
  }
#pragma unroll
  for (int q = 0; q < 4; ++q) {
    red[0][w][l][q] = x0[q]; red[0][w][l][4 + q] = x1[q];
    red[0][w][l][8 + q] = x2[q]; red[0][w][l][12 + q] = x3[q];
    red[1][w][l][q] = y0[q]; red[1][w][l][4 + q] = y1[q];
    red[1][w][l][8 + q] = y2[q]; red[1][w][l][12 + q] = y3[q];
  }
  __syncthreads();
  const int tl = threadIdx.x & 63;
  const int b = (threadIdx.x >> 6) & 3;
  const int sE = threadIdx.x >> 8;
#pragma unroll
  for (int s = 0; s < 2; ++s) {
#pragma unroll
    for (int q = 0; q < 2; ++q) {
      const int reg = (sE << 1) + q;
      const int idx = (b << 2) + reg;
      const int row = ((tl >> 4) << 2) + reg;
      float sv = 0.f, dv = 0.f;
#pragma unroll
      for (int w8 = 0; w8 < 8; ++w8) {
        sv += red[s][w8][tl][idx];
        dv += wred[s][w8][row];
      }
      dv = (dv > 0.f) ? dv : 1.f;            // defensive: avoid 0/0
      float v = sv / dv;
      v = (v > 0.f) ? v : (__expf(v) - 1.f); // ELU
      out[(size_t)(i0 + (s << 4) + row) * 64 + (b << 4) + (tl & 15)] = v;
    }
  }
}

extern "C" void kernel_launch(void* const* d_in, const int* in_sizes, int n_in,
                              void* d_out, int out_size, void* d_ws, size_t ws_size,
                              hipStream_t stream) {
  const float* h   = (const float*)d_in[0];
  const float* adj = (const float*)d_in[1];
  const float* W   = (const float*)d_in[2];
  const float* a   = (const float*)d_in[3];
  float* out = (float*)d_out;
  char* ws = (char*)d_ws;
  unsigned short* Bpack = (unsigned short*)(ws);                   // 1 MB
  unsigned short* Upack = (unsigned short*)(ws + (1u << 20));      // 1 MB
  float* expg  = (float*)(ws + (2u << 20));                        // 32 KB
  float* expg2 = (float*)(ws + (2u << 20) + 1u * 32768u);          // 32 KB
  float* Af    = (float*)(ws + (2u << 20) + 2u * 32768u);          // 32 KB
  float* Cf    = (float*)(ws + (2u << 20) + 3u * 32768u);          // 32 KB
  float* Enf   = (float*)(ws + (2u << 20) + 4u * 32768u);          // 32 KB
  u64* ML = (u64*)(ws + (3u << 20));                               // 8 MB

  hipLaunchKernelGGL(kA,  dim3(3072), dim3(256), 0, stream,
                     adj, h, W, a, ML, Bpack, expg, expg2, Af, Cf, Enf);
  hipLaunchKernelGGL(k2b, dim3(256), dim3(512), 0, stream,
                     ML, Bpack, Upack);
  hipLaunchKernelGGL(k3,  dim3(256), dim3(512), 0, stream,
                     ML, Upack, expg, expg2, Af, Cf, Enf, out);
}

// Round 13
// 133.525 us; speedup vs baseline: 1.4897x; 1.1298x over previous
//
#include <hip/hip_runtime.h>
#include <hip/hip_bf16.h>

// GAT layer, N=8192, F_IN=256, F_OUT=64.
//  kA : R10-proven wave-interleaved roles: waves 0,1 -> adj mask stream (one
//       row per wave, reg double-buffered); waves 2,3 -> k1 (scalar Wh=h@W,
//       Bpack bf16 B-frags, per-row factors expg=exp(g), expg2=exp(.2g),
//       Af=exp(f), Cf=exp(.2f), Enf=exp(-f)). No max-subtraction (|e|<=2.6,
//       softmax scale-invariant; proven by R12 absmax=0.5).
//  k2b: U = adj@Wh from bitmask via MFMA; dual row-set; fragment loads
//       register-prefetched one jb ahead (hide L2 latency under MFMA+VALU).
//  k3 : fused softmax + attention@U + ELU; factorized weights
//       w_ij=(eg_j>Enf_i)?Af_i*eg_j:Cf_i*eg2_j; denominator via ones-fragment
//       MFMA; fragment prefetch as k2b.
//
// Fragment convention (proven rounds 1/3/4/5):
//  element e of lane l <-> k = kblock*32 + (l>>4)*8 + e; A row / B col = l&15;
//  C/D: col = l&15, row = (l>>4)*4 + reg.
//  Bpack/Upack: frag[(kb*4+b)*64 + lane][e]  (s16x8 per lane)
// Mask bit (row i, col j): word ML[i*128 + (j>>8)*4 + (j&3)], bit (j>>2)&63.
//  Fragment element (r, jb, kg, e): word (jb>>3)*4 + (e&3),
//  shift = (jb&7)*8 + kg*2 + (e>>2). Pre-shift by sh0=kg*2 per chunk.

#define N 8192

typedef float f32x4 __attribute__((ext_vector_type(4)));
typedef short s16x8 __attribute__((ext_vector_type(8)));
typedef unsigned long long u64;
typedef u64 u64x2 __attribute__((ext_vector_type(2)));

union PF { s16x8 v; unsigned u[4]; };

__device__ __forceinline__ unsigned short f2bf(float x) {
  unsigned u = __float_as_uint(x);
  u += 0x7FFFu + ((u >> 16) & 1u);   // RNE
  return (unsigned short)(u >> 16);
}
__device__ __forceinline__ unsigned pack2(unsigned short lo, unsigned short hi) {
  return (unsigned)lo | ((unsigned)hi << 16);
}
// round-half-up bf16 pair pack (2 ops/elem; wt small positive => safe)
__device__ __forceinline__ unsigned packrn(float lo, float hi) {
  return ((__float_as_uint(lo) + 0x8000u) >> 16) |
         ((__float_as_uint(hi) + 0x8000u) & 0xFFFF0000u);
}

#define MFMA __builtin_amdgcn_mfma_f32_16x16x32_bf16

// ---------------- kA: wave-interleaved mask-builder + k1 (R10 structure) ----------------
__global__ __launch_bounds__(256) void kA(const float* __restrict__ adj,
                                          const float* __restrict__ h,
                                          const float* __restrict__ W,
                                          const float* __restrict__ a,
                                          u64* __restrict__ ML,
                                          unsigned short* __restrict__ Bpack,
                                          float* __restrict__ expg,
                                          float* __restrict__ expg2,
                                          float* __restrict__ Af,
                                          float* __restrict__ Cf,
                                          float* __restrict__ Enf) {
  const int l = threadIdx.x & 63;
  const int w = threadIdx.x >> 6;
  const int i = (blockIdx.x << 1) + (w & 1);   // row for this wave
  if (w < 2) {
    const float* ap = adj + (size_t)i * N + (l << 2);
    u64* mp = ML + (size_t)i * 128;
    f32x4 v0 = *(const f32x4*)(ap);
    f32x4 v1 = *(const f32x4*)(ap + 256);
    f32x4 v2 = *(const f32x4*)(ap + 512);
    f32x4 v3 = *(const f32x4*)(ap + 768);
    for (int cc = 0; cc < 32; cc += 4) {
      const int cn = (cc < 28) ? (cc + 4) : cc;   // last iter: L1-hot reload
      f32x4 n0 = *(const f32x4*)(ap + ((cn + 0) << 8));
      f32x4 n1 = *(const f32x4*)(ap + ((cn + 1) << 8));
      f32x4 n2 = *(const f32x4*)(ap + ((cn + 2) << 8));
      f32x4 n3 = *(const f32x4*)(ap + ((cn + 3) << 8));
      u64 b0  = __ballot(v0.x > 0.f), b1  = __ballot(v0.y > 0.f);
      u64 b2  = __ballot(v0.z > 0.f), b3  = __ballot(v0.w > 0.f);
      u64 b4  = __ballot(v1.x > 0.f), b5  = __ballot(v1.y > 0.f);
      u64 b6  = __ballot(v1.z > 0.f), b7  = __ballot(v1.w > 0.f);
      u64 b8  = __ballot(v2.x > 0.f), b9  = __ballot(v2.y > 0.f);
      u64 b10 = __ballot(v2.z > 0.f), b11 = __ballot(v2.w > 0.f);
      u64 b12 = __ballot(v3.x > 0.f), b13 = __ballot(v3.y > 0.f);
      u64 b14 = __ballot(v3.z > 0.f), b15 = __ballot(v3.w > 0.f);
      if (l == 0) {
        u64x2* q = (u64x2*)(mp + (cc << 2));
        u64x2 t0; t0.x = b0;  t0.y = b1;  q[0] = t0;
        u64x2 t1; t1.x = b2;  t1.y = b3;  q[1] = t1;
        u64x2 t2; t2.x = b4;  t2.y = b5;  q[2] = t2;
        u64x2 t3; t3.x = b6;  t3.y = b7;  q[3] = t3;
        u64x2 t4; t4.x = b8;  t4.y = b9;  q[4] = t4;
        u64x2 t5; t5.x = b10; t5.y = b11; q[5] = t5;
        u64x2 t6; t6.x = b12; t6.y = b13; q[6] = t6;
        u64x2 t7; t7.x = b14; t7.y = b15; q[7] = t7;
      }
      v0 = n0; v1 = n1; v2 = n2; v3 = n3;
    }
  } else {
    const float* hrow = h + (size_t)i * 256;
    float acc = 0.f;
#pragma unroll 4
    for (int kb = 0; kb < 64; ++kb) {
      f32x4 hv = *(const f32x4*)(hrow + (kb << 2));
      acc += hv.x * W[((kb << 2) + 0) * 64 + l];
      acc += hv.y * W[((kb << 2) + 1) * 64 + l];
      acc += hv.z * W[((kb << 2) + 2) * 64 + l];
      acc += hv.w * W[((kb << 2) + 3) * 64 + l];
    }
    float s1 = acc * a[l];
    float s2 = acc * a[64 + l];
#pragma unroll
    for (int d = 32; d > 0; d >>= 1) {
      s1 += __shfl_xor(s1, d);
      s2 += __shfl_xor(s2, d);
    }
    if (l == 0) {
      expg[i]  = __expf(s2);
      expg2[i] = __expf(0.2f * s2);
      Af[i]    = __expf(s1);
      Cf[i]    = __expf(0.2f * s1);
      Enf[i]   = __expf(-s1);
    }
    const int kb = i >> 5;
    const int b = l >> 4;
    const int lp = (l & 15) | (((i >> 3) & 3) << 4);
    const int e = i & 7;
    Bpack[(((size_t)(kb * 4 + b)) * 64 + lp) * 8 + e] = f2bf(acc);
  }
}

// ---------------- k2b: U from mask via MFMA, dual row-set, frag prefetch ----------------
__global__ __launch_bounds__(512) void k2b(const u64* __restrict__ ML,
                                           const unsigned short* __restrict__ Bpack,
                                           unsigned short* __restrict__ Upack) {
  __shared__ float red[2][8][64][16];   // 64 KB
  const int l = threadIdx.x & 63;
  const int w = threadIdx.x >> 6;
  const int i0 = blockIdx.x << 5;          // 32 rows/block
  const int r = l & 15, kg = l >> 4;
  const s16x8* Bv = (const s16x8*)Bpack;
  const u64x2* mrow0 = (const u64x2*)(ML + (size_t)(i0 + r) * 128);
  const u64x2* mrow1 = (const u64x2*)(ML + (size_t)(i0 + 16 + r) * 128);
  const int sh0 = kg << 1;
  f32x4 x0 = {0.f,0.f,0.f,0.f}, x1 = x0, x2 = x0, x3 = x0;
  f32x4 y0 = x0, y1 = x0, y2 = x0, y3 = x0;
  const int jb0 = w << 5;
  s16x8 c0, c1, c2, c3;
  {
    const size_t bi = ((size_t)jb0 << 8) + l;
    c0 = Bv[bi]; c1 = Bv[bi + 64]; c2 = Bv[bi + 128]; c3 = Bv[bi + 192];
  }
  for (int cc = 0; cc < 4; ++cc) {
    const int c = (w << 2) + cc;           // chunk of 256 cols
    u64x2 ma = mrow0[(c << 1)], mb = mrow0[(c << 1) + 1];
    const u64 xa0 = ma.x >> sh0, xa1 = ma.y >> sh0,
              xa2 = mb.x >> sh0, xa3 = mb.y >> sh0;
    u64x2 mc = mrow1[(c << 1)], md = mrow1[(c << 1) + 1];
    const u64 ya0 = mc.x >> sh0, ya1 = mc.y >> sh0,
              ya2 = md.x >> sh0, ya3 = md.y >> sh0;
#pragma unroll
    for (int j7 = 0; j7 < 8; ++j7) {
      const int jb = (c << 3) + j7;
      const int jbn = (cc == 3 && j7 == 7) ? jb : (jb + 1);
      const size_t bn = ((size_t)jbn << 8) + l;
      s16x8 n0 = Bv[bn], n1 = Bv[bn + 64], n2 = Bv[bn + 128], n3 = Bv[bn + 192];
      const unsigned p0 = (unsigned)(xa0 >> (j7 << 3)) & 1u;
      const unsigned p1 = (unsigned)(xa1 >> (j7 << 3)) & 1u;
      const unsigned p2 = (unsigned)(xa2 >> (j7 << 3)) & 1u;
      const unsigned p3 = (unsigned)(xa3 >> (j7 << 3)) & 1u;
      const unsigned p4 = (unsigned)(xa0 >> ((j7 << 3) + 1)) & 1u;
      const unsigned p5 = (unsigned)(xa1 >> ((j7 << 3) + 1)) & 1u;
      const unsigned p6 = (unsigned)(xa2 >> ((j7 << 3) + 1)) & 1u;
      const unsigned p7 = (unsigned)(xa3 >> ((j7 << 3) + 1)) & 1u;
      const unsigned q0 = (unsigned)(ya0 >> (j7 << 3)) & 1u;
      const unsigned q1 = (unsigned)(ya1 >> (j7 << 3)) & 1u;
      const unsigned q2 = (unsigned)(ya2 >> (j7 << 3)) & 1u;
      const unsigned q3 = (unsigned)(ya3 >> (j7 << 3)) & 1u;
      const unsigned q4 = (unsigned)(ya0 >> ((j7 << 3) + 1)) & 1u;
      const unsigned q5 = (unsigned)(ya1 >> ((j7 << 3) + 1)) & 1u;
      const unsigned q6 = (unsigned)(ya2 >> ((j7 << 3) + 1)) & 1u;
      const unsigned q7 = (unsigned)(ya3 >> ((j7 << 3) + 1)) & 1u;
      s16x8 af0, af1;
      af0[0] = p0 ? (short)0x3F80 : (short)0;
      af0[1] = p1 ? (short)0x3F80 : (short)0;
      af0[2] = p2 ? (short)0x3F80 : (short)0;
      af0[3] = p3 ? (short)0x3F80 : (short)0;
      af0[4] = p4 ? (short)0x3F80 : (short)0;
      af0[5] = p5 ? (short)0x3F80 : (short)0;
      af0[6] = p6 ? (short)0x3F80 : (short)0;
      af0[7] = p7 ? (short)0x3F80 : (short)0;
      af1[0] = q0 ? (short)0x3F80 : (short)0;
      af1[1] = q1 ? (short)0x3F80 : (short)0;
      af1[2] = q2 ? (short)0x3F80 : (short)0;
      af1[3] = q3 ? (short)0x3F80 : (short)0;
      af1[4] = q4 ? (short)0x3F80 : (short)0;
      af1[5] = q5 ? (short)0x3F80 : (short)0;
      af1[6] = q6 ? (short)0x3F80 : (short)0;
      af1[7] = q7 ? (short)0x3F80 : (short)0;
      x0 = MFMA(af0, c0, x0, 0, 0, 0);
      x1 = MFMA(af0, c1, x1, 0, 0, 0);
      x2 = MFMA(af0, c2, x2, 0, 0, 0);
      x3 = MFMA(af0, c3, x3, 0, 0, 0);
      y0 = MFMA(af1, c0, y0, 0, 0, 0);
      y1 = MFMA(af1, c1, y1, 0, 0, 0);
      y2 = MFMA(af1, c2, y2, 0, 0, 0);
      y3 = MFMA(af1, c3, y3, 0, 0, 0);
      c0 = n0; c1 = n1; c2 = n2; c3 = n3;
    }
  }
#pragma unroll
  for (int q = 0; q < 4; ++q) {
    red[0][w][l][q] = x0[q]; red[0][w][l][4 + q] = x1[q];
    red[0][w][l][8 + q] = x2[q]; red[0][w][l][12 + q] = x3[q];
    red[1][w][l][q] = y0[q]; red[1][w][l][4 + q] = y1[q];
    red[1][w][l][8 + q] = y2[q]; red[1][w][l][12 + q] = y3[q];
  }
  __syncthreads();
  const int tl = threadIdx.x & 63;
  const int b = (threadIdx.x >> 6) & 3;
  const int sE = threadIdx.x >> 8;
  const int reg0 = sE << 1;
#pragma unroll
  for (int s = 0; s < 2; ++s) {
    float u0 = 0.f, u1 = 0.f;
#pragma unroll
    for (int w8 = 0; w8 < 8; ++w8) {
      u0 += red[s][w8][tl][(b << 2) + reg0];
      u1 += red[s][w8][tl][(b << 2) + reg0 + 1];
    }
    const int k0 = i0 + (s << 4) + ((tl >> 4) << 2) + reg0;
    const unsigned pkv = pack2(f2bf(u0), f2bf(u1));
    const int kbD = k0 >> 5, lgrp = (k0 >> 3) & 3, e0 = k0 & 7;
    *(unsigned*)((char*)Upack +
        ((size_t)((kbD << 2) + b) * 64 + ((tl & 15) | (lgrp << 4))) * 16 + (e0 << 1)) = pkv;
  }
}

// ---------------- k3: fused softmax + attention@U + ELU, frag prefetch ----------------
__global__ __launch_bounds__(512) void k3(const u64* __restrict__ ML,
                                          const unsigned short* __restrict__ Upack,
                                          const float* __restrict__ expg,
                                          const float* __restrict__ expg2,
                                          const float* __restrict__ Af,
                                          const float* __restrict__ Cf,
                                          const float* __restrict__ Enf,
                                          float* __restrict__ out) {
  __shared__ float red[2][8][64][16];   // 64 KB
  __shared__ float wred[2][8][16];
  const int l = threadIdx.x & 63;
  const int w = threadIdx.x >> 6;
  const int i0 = blockIdx.x << 5;
  const int r = l & 15, kg = l >> 4;
  const float enf0 = Enf[i0 + r],      enf1 = Enf[i0 + 16 + r];
  const float Ar0 = Af[i0 + r],        Cr0 = Cf[i0 + r];
  const float Ar1 = Af[i0 + 16 + r],   Cr1 = Cf[i0 + 16 + r];
  const s16x8* Uv = (const s16x8*)Upack;
  const u64x2* mrow0 = (const u64x2*)(ML + (size_t)(i0 + r) * 128);
  const u64x2* mrow1 = (const u64x2*)(ML + (size_t)(i0 + 16 + r) * 128);
  const int sh0 = kg << 1;
  const s16x8 ones = {(short)0x3F80, (short)0x3F80, (short)0x3F80, (short)0x3F80,
                      (short)0x3F80, (short)0x3F80, (short)0x3F80, (short)0x3F80};
  f32x4 x0 = {0.f,0.f,0.f,0.f}, x1 = x0, x2 = x0, x3 = x0, xd = x0;
  f32x4 y0 = x0, y1 = x0, y2 = x0, y3 = x0, yd = x0;
  const int jb0 = w << 5;
  s16x8 c0, c1, c2, c3;
  {
    const size_t bi = ((size_t)jb0 << 8) + l;
    c0 = Uv[bi]; c1 = Uv[bi + 64]; c2 = Uv[bi + 128]; c3 = Uv[bi + 192];
  }
  for (int cc = 0; cc < 4; ++cc) {
    const int c = (w << 2) + cc;
    u64x2 ma = mrow0[(c << 1)], mb = mrow0[(c << 1) + 1];
    const u64 xa0 = ma.x >> sh0, xa1 = ma.y >> sh0,
              xa2 = mb.x >> sh0, xa3 = mb.y >> sh0;
    u64x2 mc = mrow1[(c << 1)], md = mrow1[(c << 1) + 1];
    const u64 ya0 = mc.x >> sh0, ya1 = mc.y >> sh0,
              ya2 = md.x >> sh0, ya3 = md.y >> sh0;
#pragma unroll
    for (int j7 = 0; j7 < 8; ++j7) {
      const int jb = (c << 3) + j7;
      const int jbn = (cc == 3 && j7 == 7) ? jb : (jb + 1);
      const size_t bn = ((size_t)jbn << 8) + l;
      s16x8 n0 = Uv[bn], n1 = Uv[bn + 64], n2 = Uv[bn + 128], n3 = Uv[bn + 192];
      f32x4 eg0 = *(const f32x4*)(expg + (jb << 5) + (kg << 3));
      f32x4 eg1 = *(const f32x4*)(expg + (jb << 5) + (kg << 3) + 4);
      f32x4 eh0 = *(const f32x4*)(expg2 + (jb << 5) + (kg << 3));
      f32x4 eh1 = *(const f32x4*)(expg2 + (jb << 5) + (kg << 3) + 4);
#define WT(wq, sh, egv, ehv, enf, Ar, Cr)                                    \
      ((((wq) >> (sh)) & 1ull) ?                                             \
        (((egv) > (enf)) ? (Ar) * (egv) : (Cr) * (ehv)) : 0.f)
      const float w00 = WT(xa0, (j7 << 3),     eg0.x, eh0.x, enf0, Ar0, Cr0);
      const float w01 = WT(xa1, (j7 << 3),     eg0.y, eh0.y, enf0, Ar0, Cr0);
      const float w02 = WT(xa2, (j7 << 3),     eg0.z, eh0.z, enf0, Ar0, Cr0);
      const float w03 = WT(xa3, (j7 << 3),     eg0.w, eh0.w, enf0, Ar0, Cr0);
      const float w04 = WT(xa0, (j7 << 3) + 1, eg1.x, eh1.x, enf0, Ar0, Cr0);
      const float w05 = WT(xa1, (j7 << 3) + 1, eg1.y, eh1.y, enf0, Ar0, Cr0);
      const float w06 = WT(xa2, (j7 << 3) + 1, eg1.z, eh1.z, enf0, Ar0, Cr0);
      const float w07 = WT(xa3, (j7 << 3) + 1, eg1.w, eh1.w, enf0, Ar0, Cr0);
      const float w10 = WT(ya0, (j7 << 3),     eg0.x, eh0.x, enf1, Ar1, Cr1);
      const float w11 = WT(ya1, (j7 << 3),     eg0.y, eh0.y, enf1, Ar1, Cr1);
      const float w12 = WT(ya2, (j7 << 3),     eg0.z, eh0.z, enf1, Ar1, Cr1);
      const float w13 = WT(ya3, (j7 << 3),     eg0.w, eh0.w, enf1, Ar1, Cr1);
      const float w14 = WT(ya0, (j7 << 3) + 1, eg1.x, eh1.x, enf1, Ar1, Cr1);
      const float w15 = WT(ya1, (j7 << 3) + 1, eg1.y, eh1.y, enf1, Ar1, Cr1);
      const float w16 = WT(ya2, (j7 << 3) + 1, eg1.z, eh1.z, enf1, Ar1, Cr1);
      const float w17 = WT(ya3, (j7 << 3) + 1, eg1.w, eh1.w, enf1, Ar1, Cr1);
#undef WT
      PF pf0, pf1;
      pf0.u[0] = packrn(w00, w01); pf0.u[1] = packrn(w02, w03);
      pf0.u[2] = packrn(w04, w05); pf0.u[3] = packrn(w06, w07);
      pf1.u[0] = packrn(w10, w11); pf1.u[1] = packrn(w12, w13);
      pf1.u[2] = packrn(w14, w15); pf1.u[3] = packrn(w16, w17);
      x0 = MFMA(pf0.v, c0, x0, 0, 0, 0);
      x1 = MFMA(pf0.v, c1, x1, 0, 0, 0);
      x2 = MFMA(pf0.v, c2, x2, 0, 0, 0);
      x3 = MFMA(pf0.v, c3, x3, 0, 0, 0);
      xd = MFMA(pf0.v, ones, xd, 0, 0, 0);
      y0 = MFMA(pf1.v, c0, y0, 0, 0, 0);
      y1 = MFMA(pf1.v, c1, y1, 0, 0, 0);
      y2 = MFMA(pf1.v, c2, y2, 0, 0, 0);
      y3 = MFMA(pf1.v, c3, y3, 0, 0, 0);
      yd = MFMA(pf1.v, ones, yd, 0, 0, 0);
      c0 = n0; c1 = n1; c2 = n2; c3 = n3;
    }
  }
  if (r == 0) {
#pragma unroll
    for (int q = 0; q < 4; ++q) {
      wred[0][w][(kg << 2) + q] = xd[q];   // rowsum (all cols of ones-D equal)
      wred[1][w][(kg << 2) + q] = yd[q];
    }
  }
#pragma unroll
  for (int q = 0; q < 4; ++q) {
    red[0][w][l][q] = x0[q]; red[0][w][l][4 + q] = x1[q];
    red[0][w][l][8 + q] = x2[q]; red[0][w][l][12 + q] = x3[q];
    red[1][w][l][q] = y0[q]; red[1][w][l][4 + q] = y1[q];
    red[1][w][l][8 + q] = y2[q]; red[1][w][l][12 + q] = y3[q];
  }
  __syncthreads();
  const int tl = threadIdx.x & 63;
  const int b = (threadIdx.x >> 6) & 3;
  const int sE = threadIdx.x >> 8;
#pragma unroll
  for (int s = 0; s < 2; ++s) {
#pragma unroll
    for (int q = 0; q < 2; ++q) {
      const int reg = (sE << 1) + q;
      const int idx = (b << 2) + reg;
      const int row = ((tl >> 4) << 2) + reg;
      float sv = 0.f, dv = 0.f;
#pragma unroll
      for (int w8 = 0; w8 < 8; ++w8) {
        sv += red[s][w8][tl][idx];
        dv += wred[s][w8][row];
      }
      dv = (dv > 0.f) ? dv : 1.f;            // defensive: avoid 0/0
      float v = sv / dv;
      v = (v > 0.f) ? v : (__expf(v) - 1.f); // ELU
      out[(size_t)(i0 + (s << 4) + row) * 64 + (b << 4) + (tl & 15)] = v;
    }
  }
}

extern "C" void kernel_launch(void* const* d_in, const int* in_sizes, int n_in,
                              void* d_out, int out_size, void* d_ws, size_t ws_size,
                              hipStream_t stream) {
  const float* h   = (const float*)d_in[0];
  const float* adj = (const float*)d_in[1];
  const float* W   = (const float*)d_in[2];
  const float* a   = (const float*)d_in[3];
  float* out = (float*)d_out;
  char* ws = (char*)d_ws;
  unsigned short* Bpack = (unsigned short*)(ws);                   // 1 MB
  unsigned short* Upack = (unsigned short*)(ws + (1u << 20));      // 1 MB
  float* expg  = (float*)(ws + (2u << 20));                        // 32 KB
  float* expg2 = (float*)(ws + (2u << 20) + 1u * 32768u);          // 32 KB
  float* Af    = (float*)(ws + (2u << 20) + 2u * 32768u);          // 32 KB
  float* Cf    = (float*)(ws + (2u << 20) + 3u * 32768u);          // 32 KB
  float* Enf   = (float*)(ws + (2u << 20) + 4u * 32768u);          // 32 KB
  u64* ML = (u64*)(ws + (3u << 20));                               // 8 MB

  hipLaunchKernelGGL(kA,  dim3(4096), dim3(256), 0, stream,
                     adj, h, W, a, ML, Bpack, expg, expg2, Af, Cf, Enf);
  hipLaunchKernelGGL(k2b, dim3(256), dim3(512), 0, stream,
                     ML, Bpack, Upack);
  hipLaunchKernelGGL(k3,  dim3(256), dim3(512), 0, stream,
                     ML, Upack, expg, expg2, Af, Cf, Enf, out);
}